// Round 13
// baseline (1584.051 us; speedup 1.0000x reference)
//
#include <hip/hip_runtime.h>
#include <stdint.h>

#define B_   8
#define C_   256
#define T_   8192
#define TOUT 8190

typedef float  f32x4  __attribute__((ext_vector_type(4)));
typedef float  f32x2  __attribute__((ext_vector_type(2)));
typedef __bf16 bf16x8 __attribute__((ext_vector_type(8)));

// ws layout (bytes)
#define W1_OFF 0              // 512x1536 bf16, fragment-packed: 1572864 B
#define W2_OFF 1572864        // 512x256  bf16, fragment-packed:  262144 B
#define B1_OFF 1835008        // 512 f32 stage-1 bias (f/g interleaved)
#define B2_OFF 1837056        // 512 f32 stage-2 bias (res, skip)
#define N_W1 (512 * 1536)
#define N_W2 (512 * 256)

// chunk buffer: 64 rows x 68 f32 cols (t0..t0+67) = 17408 B = 17 x 1KB units
#define BUFB 17408

static __device__ __forceinline__ unsigned short f2bf(float x) {
  union { float f; uint32_t u; } v; v.f = x;
  uint32_t r = v.u + 0x7fffu + ((v.u >> 16) & 1u);   // RNE
  return (unsigned short)(r >> 16);
}

// Pack weights into MFMA A-fragment order: frag_id = kf*32 + mf,
// within frag: lane = (kq*16 + (m&15)), elem j -> k = kf*32 + kq*8 + j.
// W1 rows interleaved: row 2c = filter(tanh) ch c, row 2c+1 = gate ch c.
// W1 k = src*512 + c_in*2 + tap  (src: 0=x,1=cin,2=gin).
__global__ __launch_bounds__(256) void prep_kernel(
    const float* w_fx, const float* w_fc, const float* w_fg,
    const float* w_gx, const float* w_gc, const float* w_gg,
    const float* b_fx, const float* b_fc, const float* b_fg,
    const float* b_gx, const float* b_gc, const float* b_gg,
    const float* w_res, const float* b_res,
    const float* w_skip, const float* b_skip,
    char* ws) {
  int idx = blockIdx.x * 256 + threadIdx.x;
  unsigned short* w1p = (unsigned short*)(ws + W1_OFF);
  unsigned short* w2p = (unsigned short*)(ws + W2_OFF);
  float* bias1 = (float*)(ws + B1_OFF);
  float* bias2 = (float*)(ws + B2_OFF);
  if (idx < N_W1) {
    int m = idx / 1536, k = idx - m * 1536;
    int src = k >> 9, rem = k & 511, ci = rem >> 1, tap = rem & 1;
    int cout = m >> 1, br = m & 1;
    const float* wp = (br == 0) ? (src == 0 ? w_fx : (src == 1 ? w_fc : w_fg))
                                : (src == 0 ? w_gx : (src == 1 ? w_gc : w_gg));
    float val = wp[cout * 512 + ci * 2 + tap];
    int mf = m >> 4, ml = m & 15, kf = k >> 5, kl = k & 31, kq = kl >> 3, j = kl & 7;
    w1p[(size_t)(kf * 32 + mf) * 512 + (kq * 16 + ml) * 8 + j] = f2bf(val);
  } else if (idx < N_W1 + N_W2) {
    int i2 = idx - N_W1;
    int m = i2 >> 8, k = i2 & 255;   // rows 0..255 = w_res, 256..511 = w_skip
    float val = (m < 256) ? w_res[m * 256 + k] : w_skip[(m - 256) * 256 + k];
    int mf = m >> 4, ml = m & 15, kf = k >> 5, kl = k & 31, kq = kl >> 3, j = kl & 7;
    w2p[(size_t)(kf * 32 + mf) * 512 + (kq * 16 + ml) * 8 + j] = f2bf(val);
  } else if (idx < N_W1 + N_W2 + 1024) {
    int i3 = idx - N_W1 - N_W2;
    if (i3 < 512) {
      int c = i3 >> 1;
      bias1[i3] = (i3 & 1) ? (b_gx[c] + b_gc[c] + b_gg[c])
                           : (b_fx[c] + b_fc[c] + b_fg[c]);
    } else {
      int m = i3 - 512;
      bias2[m] = (m < 256) ? b_res[m] : b_skip[m - 256];
    }
  }
}

// One block = (batch b, 64-wide time tile). 576 threads / 9 waves:
// waves 0-7 = compute (64 M-rows each, exactly r6's consume), wave 8 =
// PRODUCER (owns all global_load_lds staging). Rationale: vmcnt retires
// in-order, so in r6 the compiler's counted waits before MFMA (retiring
// wfr weight loads) forced retirement of the older DMA(i+1) -> zero
// prefetch window, serial [DMA][compute] per block. With the producer
// split, consumer vm queues hold only wfr+stores (waits never touch DMA);
// producer keeps 2 chunks (34 KB/block) in flight via triple buffer and
// waits vmcnt(17) per chunk (retire chunk i only; never 0 until last).
__global__ __launch_bounds__(576, 7) void wavenet_kernel(
    const float* __restrict__ x, const float* __restrict__ cin,
    const float* __restrict__ gin, const float* __restrict__ skips,
    const char* __restrict__ ws, float* __restrict__ out) {
  // 3 x 17408 B chunk buffers; Yb (64n x 512B bf16 swizzled) overlays 0-1
  __shared__ __align__(16) char smem[3 * BUFB];
  char* Yb = smem;

  const unsigned short* w1p = (const unsigned short*)(ws + W1_OFF);
  const unsigned short* w2p = (const unsigned short*)(ws + W2_OFF);
  const float* bias1 = (const float*)(ws + B1_OFF);
  const float* bias2 = (const float*)(ws + B2_OFF);

  const int tid = threadIdx.x;
  const int w = tid >> 6, lane = tid & 63, ln = lane & 15, kq = lane >> 4;
  const bool prod = (w == 8);
  // XCD-chunked swizzle (bijective, 1024 = 8*128): keeps FETCH low (r5 win)
  const int bid = blockIdx.x;
  const int swz = (bid & 7) * 128 + (bid >> 3);
  const int bb = swz >> 7, tile = swz & 127;
  const int t0 = tile * 64;
  const int valid = min(64, TOUT - t0);   // 62 on the last tile

  // slice-copy mapping (consumers, tid<512): sc = channel 0..63, sj = 0..7
  const int sc = tid >> 3, sj = tid & 7;

  float* out0 = out;                                 // res
  float* out1 = out + (size_t)B_ * C_ * TOUT;        // cin slice
  float* out2 = out + 2 * (size_t)B_ * C_ * TOUT;    // gin slice
  float* out3 = out + 3 * (size_t)B_ * C_ * TOUT;    // skips_out

  f32x4 acc[4][4];
#pragma unroll
  for (int i = 0; i < 4; ++i)
#pragma unroll
    for (int j = 0; j < 4; ++j) acc[i][j] = (f32x4){0.f, 0.f, 0.f, 0.f};

  // ---- producer: DMA one 64x68 f32 tile into buf[sel]; all 17 1KB units.
  // LDS dest = uniform base (HW adds lane*16); global src per-lane:
  // unit u, lane -> slot=(u*64+lane), row=slot/17, col=(slot%17)*4.
  auto issue = [&](int ch, int sel) {
    const int s = ch >> 2, c0 = (ch & 3) * 64;
    const float* src = (s == 0) ? x : (s == 1) ? cin : gin;
#pragma unroll
    for (int u = 0; u < 17; ++u) {
      int unit = u * 64 + lane;
      int row = unit / 17;
      int rcol = unit - row * 17;
      int tf = min(t0 + rcol * 4, T_ - 4);   // clamp: only feeds masked cols
      const float* gp = src + ((size_t)(bb * C_ + c0 + row)) * T_ + tf;
      __builtin_amdgcn_global_load_lds(
          (const __attribute__((address_space(1))) uint32_t*)gp,
          (__attribute__((address_space(3))) uint32_t*)(smem + sel * BUFB + u * 1024),
          16, 0, 0);
    }
  };

  // ---- consume chunk ch from bF: build fragments (ds_read2 + cvt) + MFMA.
  // zf elem j = src[c0 + kf*16 + kq*4 + (j>>1)][t0 + n + 2*(j&1)]
  auto consume = [&](int ch, const float* bF) {
    const int base = ch * 4;
#pragma unroll
    for (int kf = 0; kf < 4; ++kf) {
      bf16x8 wfr[4];
#pragma unroll
      for (int mi = 0; mi < 4; ++mi)
        wfr[mi] = *(const bf16x8*)
            &w1p[(size_t)((base + kf) * 32 + (w * 4 + mi)) * 512 + lane * 8];
#pragma unroll
      for (int ni = 0; ni < 4; ++ni) {
        const int nn = ni * 16 + ln;
        bf16x8 zf;
#pragma unroll
        for (int cc = 0; cc < 4; ++cc) {
          const float* rp = bF + (kf * 16 + kq * 4 + cc) * 68 + nn;
          zf[2 * cc]     = (__bf16)rp[0];
          zf[2 * cc + 1] = (__bf16)rp[2];
        }
#pragma unroll
        for (int mi = 0; mi < 4; ++mi)
          acc[mi][ni] = __builtin_amdgcn_mfma_f32_16x16x32_bf16(
              wfr[mi], zf, acc[mi][ni], 0, 0, 0);
      }
    }
  };

  // ---- cin/gin slice copy straight from the LDS tile (consumers) ----
  auto slice = [&](int ch, const float* bF) {
    const int s = ch >> 2;
    if (s == 0) return;
    const int c0 = (ch & 3) * 64;
    float* o = (s == 1 ? out1 : out2) +
               ((size_t)(bb * C_ + c0 + sc)) * TOUT + t0 + sj * 8;
    float v[8];
#pragma unroll
    for (int m = 0; m < 8; ++m) v[m] = bF[sc * 68 + sj * 8 + 2 + m];
#pragma unroll
    for (int p = 0; p < 4; ++p) {
      if (t0 + sj * 8 + 2 * p + 1 < TOUT) {
        f32x2 q = {v[2 * p], v[2 * p + 1]};
        *(f32x2*)(o + 2 * p) = q;     // 8B-aligned (row base dword even)
      }
    }
  };

  // ---- stage 1: producer-consumer, triple buffer, 1 barrier/chunk ----
  if (prod) { issue(0, 0); issue(1, 1); }
  for (int i = 0; i < 12; ++i) {
    if (prod) {
      // Producer queue oldest->newest: [DMA(i):17][DMA(i+1):17 (if issued)].
      // vmcnt(17) retires exactly DMA(i); DMA(i+1) stays in flight.
      // Last chunk: only DMA(11) outstanding -> must drain to 0.
      __builtin_amdgcn_sched_barrier(0);
      if (i == 11) asm volatile("s_waitcnt vmcnt(0)" ::: "memory");
      else         asm volatile("s_waitcnt vmcnt(17)" ::: "memory");
      __builtin_amdgcn_sched_barrier(0);
    }
    __builtin_amdgcn_s_barrier();      // buf i%3 ready; buf (i+2)%3 free
    __builtin_amdgcn_sched_barrier(0);
    if (prod) {
      if (i + 2 < 12) issue(i + 2, (i + 2) % 3);
    } else {
      const float* bF = (const float*)(smem + (i % 3) * BUFB);
      consume(i, bF);
      slice(i, bF);
    }
  }

  __syncthreads();   // all chunk reads done before Yb overlays buffers

  // ---- epilogue 1: bias + tanh*sigmoid -> Yb (bf16, swizzled) ----
  if (w < 8) {
#pragma unroll
    for (int mi = 0; mi < 4; ++mi) {
      const int mbase = w * 64 + mi * 16 + kq * 4;   // multiple of 4
      const f32x4 b4 = *(const f32x4*)&bias1[mbase];
#pragma unroll
      for (int ni = 0; ni < 4; ++ni) {
        f32x4 v = acc[mi][ni];
        float f0 = v.x + b4.x, g0 = v.y + b4.y, f1 = v.z + b4.z, g1 = v.w + b4.w;
        float y0 = (2.f / (1.f + __expf(-2.f * f0)) - 1.f) * (1.f / (1.f + __expf(-g0)));
        float y1 = (2.f / (1.f + __expf(-2.f * f1)) - 1.f) * (1.f / (1.f + __expf(-g1)));
        int n = ni * 16 + ln;
        uint32_t pk = (uint32_t)f2bf(y0) | ((uint32_t)f2bf(y1) << 16);
        int boff = (n * 512 + mbase) ^ ((n & 7) << 4);   // ch pair at byte mbase
        *(uint32_t*)(Yb + boff) = pk;
      }
    }
  }
  __syncthreads();

  // ---- stage 2: [res;skip] = W2 * Y + epilogue 2 (compute waves only) ----
  if (w < 8) {
    f32x4 acc2[4][4];
#pragma unroll
    for (int i = 0; i < 4; ++i)
#pragma unroll
      for (int j = 0; j < 4; ++j) acc2[i][j] = (f32x4){0.f, 0.f, 0.f, 0.f};

#pragma unroll
    for (int kf = 0; kf < 8; ++kf) {
      bf16x8 zfr[4];
#pragma unroll
      for (int ni = 0; ni < 4; ++ni) {
        int n = ni * 16 + ln;
        int boff = (n * 512 + kf * 64 + kq * 16) ^ ((n & 7) << 4);
        zfr[ni] = *(const bf16x8*)(Yb + boff);
      }
      bf16x8 wfr[4];
#pragma unroll
      for (int mi = 0; mi < 4; ++mi)
        wfr[mi] = *(const bf16x8*)
            &w2p[(size_t)(kf * 32 + (w * 4 + mi)) * 512 + lane * 8];
#pragma unroll
      for (int mi = 0; mi < 4; ++mi)
#pragma unroll
        for (int ni = 0; ni < 4; ++ni)
          acc2[mi][ni] = __builtin_amdgcn_mfma_f32_16x16x32_bf16(
              wfr[mi], zfr[ni], acc2[mi][ni], 0, 0, 0);
    }

    // bias + residual adds, store res / skips_out
#pragma unroll
    for (int mi = 0; mi < 4; ++mi) {
      const int mbase = w * 64 + mi * 16 + kq * 4;
      const f32x4 b4 = *(const f32x4*)&bias2[mbase];
#pragma unroll
      for (int r = 0; r < 4; ++r) {
        const int m2 = mbase + r;
        const int isres = (m2 < 256);            // uniform per wave (w<4)
        const int crow = isres ? m2 : m2 - 256;
        const float* ap = (isres ? x : skips) + ((size_t)(bb * C_ + crow)) * T_ + t0 + 2;
        float* dp = (isres ? out0 : out3) + ((size_t)(bb * C_ + crow)) * TOUT + t0;
        const float bs = b4[r];
#pragma unroll
        for (int ni = 0; ni < 4; ++ni) {
          int n = ni * 16 + ln;
          if (n < valid) dp[n] = acc2[mi][ni][r] + bs + ap[n];
        }
      }
    }
  }
}

extern "C" void kernel_launch(void* const* d_in, const int* in_sizes, int n_in,
                              void* d_out, int out_size, void* d_ws, size_t ws_size,
                              hipStream_t stream) {
  const float* xx    = (const float*)d_in[0];
  const float* cin   = (const float*)d_in[1];
  const float* gin   = (const float*)d_in[2];
  const float* skips = (const float*)d_in[3];
  const float* w_fx = (const float*)d_in[4],  *b_fx = (const float*)d_in[5];
  const float* w_fc = (const float*)d_in[6],  *b_fc = (const float*)d_in[7];
  const float* w_fg = (const float*)d_in[8],  *b_fg = (const float*)d_in[9];
  const float* w_gx = (const float*)d_in[10], *b_gx = (const float*)d_in[11];
  const float* w_gc = (const float*)d_in[12], *b_gc = (const float*)d_in[13];
  const float* w_gg = (const float*)d_in[14], *b_gg = (const float*)d_in[15];
  const float* w_res  = (const float*)d_in[16], *b_res  = (const float*)d_in[17];
  const float* w_skip = (const float*)d_in[18], *b_skip = (const float*)d_in[19];
  char* ws = (char*)d_ws;
  float* outp = (float*)d_out;

  prep_kernel<<<(N_W1 + N_W2 + 1024) / 256, 256, 0, stream>>>(
      w_fx, w_fc, w_fg, w_gx, w_gc, w_gg,
      b_fx, b_fc, b_fg, b_gx, b_gc, b_gg,
      w_res, b_res, w_skip, b_skip, ws);

  // 8 batches x 128 time-tiles of 64 (XCD-chunk-swizzled in-kernel)
  wavenet_kernel<<<1024, 576, 0, stream>>>(xx, cin, gin, skips, ws, outp);
}

// Round 14
// 465.919 us; speedup vs baseline: 3.3998x; 3.3998x over previous
//
#include <hip/hip_runtime.h>
#include <stdint.h>

#define B_   8
#define C_   256
#define T_   8192
#define TOUT 8190

typedef float  f32x4  __attribute__((ext_vector_type(4)));
typedef float  f32x2  __attribute__((ext_vector_type(2)));
typedef __bf16 bf16x8 __attribute__((ext_vector_type(8)));

// ws layout (bytes)
#define W1_OFF 0              // 512x1536 bf16, fragment-packed: 1572864 B
#define W2_OFF 1572864        // 512x256  bf16, fragment-packed:  262144 B
#define B1_OFF 1835008        // 512 f32 stage-1 bias (f/g interleaved)
#define B2_OFF 1837056        // 512 f32 stage-2 bias (res, skip)
#define N_W1 (512 * 1536)
#define N_W2 (512 * 256)

// chunk buffer: 64 rows x 68 f32 cols (t0..t0+67) = 17408 B = 17 x 1KB units
#define BUFB 17408

static __device__ __forceinline__ unsigned short f2bf(float x) {
  union { float f; uint32_t u; } v; v.f = x;
  uint32_t r = v.u + 0x7fffu + ((v.u >> 16) & 1u);   // RNE
  return (unsigned short)(r >> 16);
}

// Pack weights into MFMA A-fragment order: frag_id = kf*32 + mf,
// within frag: lane = (kq*16 + (m&15)), elem j -> k = kf*32 + kq*8 + j.
// W1 rows interleaved: row 2c = filter(tanh) ch c, row 2c+1 = gate ch c.
// W1 k = src*512 + c_in*2 + tap  (src: 0=x,1=cin,2=gin).
__global__ __launch_bounds__(256) void prep_kernel(
    const float* w_fx, const float* w_fc, const float* w_fg,
    const float* w_gx, const float* w_gc, const float* w_gg,
    const float* b_fx, const float* b_fc, const float* b_fg,
    const float* b_gx, const float* b_gc, const float* b_gg,
    const float* w_res, const float* b_res,
    const float* w_skip, const float* b_skip,
    char* ws) {
  int idx = blockIdx.x * 256 + threadIdx.x;
  unsigned short* w1p = (unsigned short*)(ws + W1_OFF);
  unsigned short* w2p = (unsigned short*)(ws + W2_OFF);
  float* bias1 = (float*)(ws + B1_OFF);
  float* bias2 = (float*)(ws + B2_OFF);
  if (idx < N_W1) {
    int m = idx / 1536, k = idx - m * 1536;
    int src = k >> 9, rem = k & 511, ci = rem >> 1, tap = rem & 1;
    int cout = m >> 1, br = m & 1;
    const float* wp = (br == 0) ? (src == 0 ? w_fx : (src == 1 ? w_fc : w_fg))
                                : (src == 0 ? w_gx : (src == 1 ? w_gc : w_gg));
    float val = wp[cout * 512 + ci * 2 + tap];
    int mf = m >> 4, ml = m & 15, kf = k >> 5, kl = k & 31, kq = kl >> 3, j = kl & 7;
    w1p[(size_t)(kf * 32 + mf) * 512 + (kq * 16 + ml) * 8 + j] = f2bf(val);
  } else if (idx < N_W1 + N_W2) {
    int i2 = idx - N_W1;
    int m = i2 >> 8, k = i2 & 255;   // rows 0..255 = w_res, 256..511 = w_skip
    float val = (m < 256) ? w_res[m * 256 + k] : w_skip[(m - 256) * 256 + k];
    int mf = m >> 4, ml = m & 15, kf = k >> 5, kl = k & 31, kq = kl >> 3, j = kl & 7;
    w2p[(size_t)(kf * 32 + mf) * 512 + (kq * 16 + ml) * 8 + j] = f2bf(val);
  } else if (idx < N_W1 + N_W2 + 1024) {
    int i3 = idx - N_W1 - N_W2;
    if (i3 < 512) {
      int c = i3 >> 1;
      bias1[i3] = (i3 & 1) ? (b_gx[c] + b_gc[c] + b_gg[c])
                           : (b_fx[c] + b_fc[c] + b_fg[c]);
    } else {
      int m = i3 - 512;
      bias2[m] = (m < 256) ? b_res[m] : b_skip[m - 256];
    }
  }
}

// One block = (batch b, 64-wide time tile). 576 threads / 9 waves:
// waves 0-7 = compute (64 M-rows each, exactly r6's consume), wave 8 =
// PRODUCER (owns all global_load_lds staging). Rationale: vmcnt retires
// in-order, so in r6 the compiler's counted waits before MFMA (retiring
// wfr weight loads) forced retirement of the older DMA(i+1) -> zero
// prefetch window, serial [DMA][compute] per block. With the producer
// split, consumer vm queues hold only wfr+stores (waits never touch DMA);
// producer keeps 2 chunks (34 KB/block) in flight via triple buffer and
// waits vmcnt(17) per chunk (retire chunk i only; never 0 until last).
// launch_bounds(576,4): VGPR cap 128 (r13's (576,7) capped ~73 -> acc
// spilled to scratch -> 5.8 GB spill traffic, 10x regression).
__global__ __launch_bounds__(576, 4) void wavenet_kernel(
    const float* __restrict__ x, const float* __restrict__ cin,
    const float* __restrict__ gin, const float* __restrict__ skips,
    const char* __restrict__ ws, float* __restrict__ out) {
  // 3 x 17408 B chunk buffers; Yb (64n x 512B bf16 swizzled) overlays 0-1
  __shared__ __align__(16) char smem[3 * BUFB];
  char* Yb = smem;

  const unsigned short* w1p = (const unsigned short*)(ws + W1_OFF);
  const unsigned short* w2p = (const unsigned short*)(ws + W2_OFF);
  const float* bias1 = (const float*)(ws + B1_OFF);
  const float* bias2 = (const float*)(ws + B2_OFF);

  const int tid = threadIdx.x;
  const int w = tid >> 6, lane = tid & 63, ln = lane & 15, kq = lane >> 4;
  const bool prod = (w == 8);
  // XCD-chunked swizzle (bijective, 1024 = 8*128): keeps FETCH low (r5 win)
  const int bid = blockIdx.x;
  const int swz = (bid & 7) * 128 + (bid >> 3);
  const int bb = swz >> 7, tile = swz & 127;
  const int t0 = tile * 64;
  const int valid = min(64, TOUT - t0);   // 62 on the last tile

  // slice-copy mapping (consumers, tid<512): sc = channel 0..63, sj = 0..7
  const int sc = tid >> 3, sj = tid & 7;

  float* out0 = out;                                 // res
  float* out1 = out + (size_t)B_ * C_ * TOUT;        // cin slice
  float* out2 = out + 2 * (size_t)B_ * C_ * TOUT;    // gin slice
  float* out3 = out + 3 * (size_t)B_ * C_ * TOUT;    // skips_out

  f32x4 acc[4][4];
#pragma unroll
  for (int i = 0; i < 4; ++i)
#pragma unroll
    for (int j = 0; j < 4; ++j) acc[i][j] = (f32x4){0.f, 0.f, 0.f, 0.f};

  // ---- producer: DMA one 64x68 f32 tile into buf[sel]; all 17 1KB units.
  // LDS dest = uniform base (HW adds lane*16); global src per-lane:
  // unit u, lane -> slot=(u*64+lane), row=slot/17, col=(slot%17)*4.
  auto issue = [&](int ch, int sel) {
    const int s = ch >> 2, c0 = (ch & 3) * 64;
    const float* src = (s == 0) ? x : (s == 1) ? cin : gin;
#pragma unroll
    for (int u = 0; u < 17; ++u) {
      int unit = u * 64 + lane;
      int row = unit / 17;
      int rcol = unit - row * 17;
      int tf = min(t0 + rcol * 4, T_ - 4);   // clamp: only feeds masked cols
      const float* gp = src + ((size_t)(bb * C_ + c0 + row)) * T_ + tf;
      __builtin_amdgcn_global_load_lds(
          (const __attribute__((address_space(1))) uint32_t*)gp,
          (__attribute__((address_space(3))) uint32_t*)(smem + sel * BUFB + u * 1024),
          16, 0, 0);
    }
  };

  // ---- consume chunk ch from bF: build fragments (ds_read2 + cvt) + MFMA.
  // zf elem j = src[c0 + kf*16 + kq*4 + (j>>1)][t0 + n + 2*(j&1)]
  auto consume = [&](int ch, const float* bF) {
    const int base = ch * 4;
#pragma unroll
    for (int kf = 0; kf < 4; ++kf) {
      bf16x8 wfr[4];
#pragma unroll
      for (int mi = 0; mi < 4; ++mi)
        wfr[mi] = *(const bf16x8*)
            &w1p[(size_t)((base + kf) * 32 + (w * 4 + mi)) * 512 + lane * 8];
#pragma unroll
      for (int ni = 0; ni < 4; ++ni) {
        const int nn = ni * 16 + ln;
        bf16x8 zf;
#pragma unroll
        for (int cc = 0; cc < 4; ++cc) {
          const float* rp = bF + (kf * 16 + kq * 4 + cc) * 68 + nn;
          zf[2 * cc]     = (__bf16)rp[0];
          zf[2 * cc + 1] = (__bf16)rp[2];
        }
#pragma unroll
        for (int mi = 0; mi < 4; ++mi)
          acc[mi][ni] = __builtin_amdgcn_mfma_f32_16x16x32_bf16(
              wfr[mi], zf, acc[mi][ni], 0, 0, 0);
      }
    }
  };

  // ---- cin/gin slice copy straight from the LDS tile (consumers) ----
  auto slice = [&](int ch, const float* bF) {
    const int s = ch >> 2;
    if (s == 0) return;
    const int c0 = (ch & 3) * 64;
    float* o = (s == 1 ? out1 : out2) +
               ((size_t)(bb * C_ + c0 + sc)) * TOUT + t0 + sj * 8;
    float v[8];
#pragma unroll
    for (int m = 0; m < 8; ++m) v[m] = bF[sc * 68 + sj * 8 + 2 + m];
#pragma unroll
    for (int p = 0; p < 4; ++p) {
      if (t0 + sj * 8 + 2 * p + 1 < TOUT) {
        f32x2 q = {v[2 * p], v[2 * p + 1]};
        *(f32x2*)(o + 2 * p) = q;     // 8B-aligned (row base dword even)
      }
    }
  };

  // ---- stage 1: producer-consumer, triple buffer, 1 barrier/chunk ----
  if (prod) { issue(0, 0); issue(1, 1); }
  for (int i = 0; i < 12; ++i) {
    if (prod) {
      // Producer queue oldest->newest: [DMA(i):17][DMA(i+1):17 (if issued)].
      // vmcnt(17) retires exactly DMA(i); DMA(i+1) stays in flight.
      // Last chunk: only DMA(11) outstanding -> must drain to 0.
      __builtin_amdgcn_sched_barrier(0);
      if (i == 11) asm volatile("s_waitcnt vmcnt(0)" ::: "memory");
      else         asm volatile("s_waitcnt vmcnt(17)" ::: "memory");
      __builtin_amdgcn_sched_barrier(0);
    }
    __builtin_amdgcn_s_barrier();      // buf i%3 ready; buf (i+2)%3 free
    __builtin_amdgcn_sched_barrier(0);
    if (prod) {
      if (i + 2 < 12) issue(i + 2, (i + 2) % 3);
    } else {
      const float* bF = (const float*)(smem + (i % 3) * BUFB);
      consume(i, bF);
      slice(i, bF);
    }
  }

  __syncthreads();   // all chunk reads done before Yb overlays buffers

  // ---- epilogue 1: bias + tanh*sigmoid -> Yb (bf16, swizzled) ----
  if (w < 8) {
#pragma unroll
    for (int mi = 0; mi < 4; ++mi) {
      const int mbase = w * 64 + mi * 16 + kq * 4;   // multiple of 4
      const f32x4 b4 = *(const f32x4*)&bias1[mbase];
#pragma unroll
      for (int ni = 0; ni < 4; ++ni) {
        f32x4 v = acc[mi][ni];
        float f0 = v.x + b4.x, g0 = v.y + b4.y, f1 = v.z + b4.z, g1 = v.w + b4.w;
        float y0 = (2.f / (1.f + __expf(-2.f * f0)) - 1.f) * (1.f / (1.f + __expf(-g0)));
        float y1 = (2.f / (1.f + __expf(-2.f * f1)) - 1.f) * (1.f / (1.f + __expf(-g1)));
        int n = ni * 16 + ln;
        uint32_t pk = (uint32_t)f2bf(y0) | ((uint32_t)f2bf(y1) << 16);
        int boff = (n * 512 + mbase) ^ ((n & 7) << 4);   // ch pair at byte mbase
        *(uint32_t*)(Yb + boff) = pk;
      }
    }
  }
  __syncthreads();

  // ---- stage 2: [res;skip] = W2 * Y + epilogue 2 (compute waves only) ----
  if (w < 8) {
    f32x4 acc2[4][4];
#pragma unroll
    for (int i = 0; i < 4; ++i)
#pragma unroll
      for (int j = 0; j < 4; ++j) acc2[i][j] = (f32x4){0.f, 0.f, 0.f, 0.f};

#pragma unroll
    for (int kf = 0; kf < 8; ++kf) {
      bf16x8 zfr[4];
#pragma unroll
      for (int ni = 0; ni < 4; ++ni) {
        int n = ni * 16 + ln;
        int boff = (n * 512 + kf * 64 + kq * 16) ^ ((n & 7) << 4);
        zfr[ni] = *(const bf16x8*)(Yb + boff);
      }
      bf16x8 wfr[4];
#pragma unroll
      for (int mi = 0; mi < 4; ++mi)
        wfr[mi] = *(const bf16x8*)
            &w2p[(size_t)(kf * 32 + (w * 4 + mi)) * 512 + lane * 8];
#pragma unroll
      for (int mi = 0; mi < 4; ++mi)
#pragma unroll
        for (int ni = 0; ni < 4; ++ni)
          acc2[mi][ni] = __builtin_amdgcn_mfma_f32_16x16x32_bf16(
              wfr[mi], zfr[ni], acc2[mi][ni], 0, 0, 0);
    }

    // bias + residual adds, store res / skips_out
#pragma unroll
    for (int mi = 0; mi < 4; ++mi) {
      const int mbase = w * 64 + mi * 16 + kq * 4;
      const f32x4 b4 = *(const f32x4*)&bias2[mbase];
#pragma unroll
      for (int r = 0; r < 4; ++r) {
        const int m2 = mbase + r;
        const int isres = (m2 < 256);            // uniform per wave (w<4)
        const int crow = isres ? m2 : m2 - 256;
        const float* ap = (isres ? x : skips) + ((size_t)(bb * C_ + crow)) * T_ + t0 + 2;
        float* dp = (isres ? out0 : out3) + ((size_t)(bb * C_ + crow)) * TOUT + t0;
        const float bs = b4[r];
#pragma unroll
        for (int ni = 0; ni < 4; ++ni) {
          int n = ni * 16 + ln;
          if (n < valid) dp[n] = acc2[mi][ni][r] + bs + ap[n];
        }
      }
    }
  }
}

extern "C" void kernel_launch(void* const* d_in, const int* in_sizes, int n_in,
                              void* d_out, int out_size, void* d_ws, size_t ws_size,
                              hipStream_t stream) {
  const float* xx    = (const float*)d_in[0];
  const float* cin   = (const float*)d_in[1];
  const float* gin   = (const float*)d_in[2];
  const float* skips = (const float*)d_in[3];
  const float* w_fx = (const float*)d_in[4],  *b_fx = (const float*)d_in[5];
  const float* w_fc = (const float*)d_in[6],  *b_fc = (const float*)d_in[7];
  const float* w_fg = (const float*)d_in[8],  *b_fg = (const float*)d_in[9];
  const float* w_gx = (const float*)d_in[10], *b_gx = (const float*)d_in[11];
  const float* w_gc = (const float*)d_in[12], *b_gc = (const float*)d_in[13];
  const float* w_gg = (const float*)d_in[14], *b_gg = (const float*)d_in[15];
  const float* w_res  = (const float*)d_in[16], *b_res  = (const float*)d_in[17];
  const float* w_skip = (const float*)d_in[18], *b_skip = (const float*)d_in[19];
  char* ws = (char*)d_ws;
  float* outp = (float*)d_out;

  prep_kernel<<<(N_W1 + N_W2 + 1024) / 256, 256, 0, stream>>>(
      w_fx, w_fc, w_fg, w_gx, w_gc, w_gg,
      b_fx, b_fc, b_fg, b_gx, b_gc, b_gg,
      w_res, b_res, w_skip, b_skip, ws);

  // 8 batches x 128 time-tiles of 64 (XCD-chunk-swizzled in-kernel)
  wavenet_kernel<<<1024, 576, 0, stream>>>(xx, cin, gin, skips, ws, outp);
}

// Round 15
// 269.113 us; speedup vs baseline: 5.8862x; 1.7313x over previous
//
#include <hip/hip_runtime.h>
#include <stdint.h>

#define B_   8
#define C_   256
#define T_   8192
#define TOUT 8190

typedef float  f32x4  __attribute__((ext_vector_type(4)));
typedef float  f32x2  __attribute__((ext_vector_type(2)));
typedef __bf16 bf16x8 __attribute__((ext_vector_type(8)));

// ws layout (bytes)
#define W1_OFF 0              // 512x1536 bf16, fragment-packed: 1572864 B
#define W2_OFF 1572864        // 512x256  bf16, fragment-packed:  262144 B
#define B1_OFF 1835008        // 512 f32 stage-1 bias (f/g interleaved)
#define B2_OFF 1837056        // 512 f32 stage-2 bias (res, skip)
#define N_W1 (512 * 1536)
#define N_W2 (512 * 256)

// chunk buffer: 64 rows x 68 f32 cols (t0..t0+67) = 17408 B = 17 x 1KB units
#define BUFB 17408

static __device__ __forceinline__ unsigned short f2bf(float x) {
  union { float f; uint32_t u; } v; v.f = x;
  uint32_t r = v.u + 0x7fffu + ((v.u >> 16) & 1u);   // RNE
  return (unsigned short)(r >> 16);
}

// Pack weights into MFMA A-fragment order: frag_id = kf*32 + mf,
// within frag: lane = (kq*16 + (m&15)), elem j -> k = kf*32 + kq*8 + j.
// W1 rows interleaved: row 2c = filter(tanh) ch c, row 2c+1 = gate ch c.
// W1 k = src*512 + c_in*2 + tap  (src: 0=x,1=cin,2=gin).
__global__ __launch_bounds__(256) void prep_kernel(
    const float* w_fx, const float* w_fc, const float* w_fg,
    const float* w_gx, const float* w_gc, const float* w_gg,
    const float* b_fx, const float* b_fc, const float* b_fg,
    const float* b_gx, const float* b_gc, const float* b_gg,
    const float* w_res, const float* b_res,
    const float* w_skip, const float* b_skip,
    char* ws) {
  int idx = blockIdx.x * 256 + threadIdx.x;
  unsigned short* w1p = (unsigned short*)(ws + W1_OFF);
  unsigned short* w2p = (unsigned short*)(ws + W2_OFF);
  float* bias1 = (float*)(ws + B1_OFF);
  float* bias2 = (float*)(ws + B2_OFF);
  if (idx < N_W1) {
    int m = idx / 1536, k = idx - m * 1536;
    int src = k >> 9, rem = k & 511, ci = rem >> 1, tap = rem & 1;
    int cout = m >> 1, br = m & 1;
    const float* wp = (br == 0) ? (src == 0 ? w_fx : (src == 1 ? w_fc : w_fg))
                                : (src == 0 ? w_gx : (src == 1 ? w_gc : w_gg));
    float val = wp[cout * 512 + ci * 2 + tap];
    int mf = m >> 4, ml = m & 15, kf = k >> 5, kl = k & 31, kq = kl >> 3, j = kl & 7;
    w1p[(size_t)(kf * 32 + mf) * 512 + (kq * 16 + ml) * 8 + j] = f2bf(val);
  } else if (idx < N_W1 + N_W2) {
    int i2 = idx - N_W1;
    int m = i2 >> 8, k = i2 & 255;   // rows 0..255 = w_res, 256..511 = w_skip
    float val = (m < 256) ? w_res[m * 256 + k] : w_skip[(m - 256) * 256 + k];
    int mf = m >> 4, ml = m & 15, kf = k >> 5, kl = k & 31, kq = kl >> 3, j = kl & 7;
    w2p[(size_t)(kf * 32 + mf) * 512 + (kq * 16 + ml) * 8 + j] = f2bf(val);
  } else if (idx < N_W1 + N_W2 + 1024) {
    int i3 = idx - N_W1 - N_W2;
    if (i3 < 512) {
      int c = i3 >> 1;
      bias1[i3] = (i3 & 1) ? (b_gx[c] + b_gc[c] + b_gg[c])
                           : (b_fx[c] + b_fc[c] + b_fg[c]);
    } else {
      int m = i3 - 512;
      bias2[m] = (m < 256) ? b_res[m] : b_skip[m - 256];
    }
  }
}

// One block = (batch b, 64-wide time tile). 512 threads / 8 waves.
// Stage1 K-loop: 12 chunks (src s=ch>>2, 64-channel group). Each chunk's
// 64x68 f32 source tile is DMA'd global->LDS via global_load_lds (width 16,
// no VGPR round-trip); bf16 conversion happens at fragment-build (ds_read2
// + cvt_pk). Double-buffered, ONE raw s_barrier per chunk, counted vmcnt
// (never 0 after peel) so loads/stores stay in flight across barriers.
// Stage2: [res;skip](512x64) = W2(512x256)*Y, Y in LDS (reuses buffers).
__global__ __launch_bounds__(512, 4) void wavenet_kernel(
    const float* __restrict__ x, const float* __restrict__ cin,
    const float* __restrict__ gin, const float* __restrict__ skips,
    const char* __restrict__ ws, float* __restrict__ out) {
  // 2 x 17408 B chunk buffers; Yb (64n x 512B bf16 swizzled) overlays them
  __shared__ __align__(16) char smem[2 * BUFB];
  char* Yb = smem;

  const unsigned short* w1p = (const unsigned short*)(ws + W1_OFF);
  const unsigned short* w2p = (const unsigned short*)(ws + W2_OFF);
  const float* bias1 = (const float*)(ws + B1_OFF);
  const float* bias2 = (const float*)(ws + B2_OFF);

  const int tid = threadIdx.x;
  const int w = tid >> 6, lane = tid & 63, ln = lane & 15, kq = lane >> 4;
  // XCD-chunked swizzle (bijective, 1024 = 8*128): keeps FETCH low (r5 win)
  const int bid = blockIdx.x;
  const int swz = (bid & 7) * 128 + (bid >> 3);
  const int bb = swz >> 7, tile = swz & 127;
  const int t0 = tile * 64;
  const int valid = min(64, TOUT - t0);   // 62 on the last tile

  // slice-copy mapping: sc = channel-in-group (0..63), sj = t-octet (0..7)
  const int sc = tid >> 3, sj = tid & 7;

  float* out0 = out;                                 // res
  float* out1 = out + (size_t)B_ * C_ * TOUT;        // cin slice
  float* out2 = out + 2 * (size_t)B_ * C_ * TOUT;    // gin slice
  float* out3 = out + 3 * (size_t)B_ * C_ * TOUT;    // skips_out

  f32x4 acc[4][4];
#pragma unroll
  for (int i = 0; i < 4; ++i)
#pragma unroll
    for (int j = 0; j < 4; ++j) acc[i][j] = (f32x4){0.f, 0.f, 0.f, 0.f};

  // ---- DMA one 64x68 f32 tile into buf[sel]; 17 1KB units, wave w does
  // units {w, w+8, w+16<17}. LDS dest = uniform base (HW adds lane*16);
  // global src per-lane: unit u, lane -> row=(u*64+lane)/17, col rem*4.
  auto issue = [&](int ch, int sel) {
    const int s = ch >> 2, c0 = (ch & 3) * 64;
    const float* src = (s == 0) ? x : (s == 1) ? cin : gin;
#pragma unroll
    for (int u = w; u < 17; u += 8) {
      int unit = u * 64 + lane;
      int row = unit / 17;
      int rcol = unit - row * 17;
      int tf = min(t0 + rcol * 4, T_ - 4);   // clamp: only feeds masked cols
      const float* gp = src + ((size_t)(bb * C_ + c0 + row)) * T_ + tf;
      __builtin_amdgcn_global_load_lds(
          (const __attribute__((address_space(1))) uint32_t*)gp,
          (__attribute__((address_space(3))) uint32_t*)(smem + sel * BUFB + u * 1024),
          16, 0, 0);
    }
  };

  // ---- consume chunk ch from bF: build fragments (ds_read2 + cvt) + MFMA.
  // zf elem j = src[c0 + kf*16 + kq*4 + (j>>1)][t0 + n + 2*(j&1)]
  auto consume = [&](int ch, const float* bF) {
    const int base = ch * 4;
#pragma unroll
    for (int kf = 0; kf < 4; ++kf) {
      bf16x8 wfr[4];
#pragma unroll
      for (int mi = 0; mi < 4; ++mi)
        wfr[mi] = *(const bf16x8*)
            &w1p[(size_t)((base + kf) * 32 + (w * 4 + mi)) * 512 + lane * 8];
#pragma unroll
      for (int ni = 0; ni < 4; ++ni) {
        const int nn = ni * 16 + ln;
        bf16x8 zf;
#pragma unroll
        for (int cc = 0; cc < 4; ++cc) {
          const float* rp = bF + (kf * 16 + kq * 4 + cc) * 68 + nn;
          zf[2 * cc]     = (__bf16)rp[0];
          zf[2 * cc + 1] = (__bf16)rp[2];
        }
#pragma unroll
        for (int mi = 0; mi < 4; ++mi)
          acc[mi][ni] = __builtin_amdgcn_mfma_f32_16x16x32_bf16(
              wfr[mi], zf, acc[mi][ni], 0, 0, 0);
      }
    }
  };

  // ---- cin/gin slice copy straight from the LDS tile ----
  auto slice = [&](int ch, const float* bF) {
    const int s = ch >> 2;
    if (s == 0) return;
    const int c0 = (ch & 3) * 64;
    float* o = (s == 1 ? out1 : out2) +
               ((size_t)(bb * C_ + c0 + sc)) * TOUT + t0 + sj * 8;
    float v[8];
#pragma unroll
    for (int m = 0; m < 8; ++m) v[m] = bF[sc * 68 + sj * 8 + 2 + m];
#pragma unroll
    for (int p = 0; p < 4; ++p) {
      if (t0 + sj * 8 + 2 * p + 1 < TOUT) {
        f32x2 q = {v[2 * p], v[2 * p + 1]};
        *(f32x2*)(o + 2 * p) = q;     // 8B-aligned (row base dword even)
      }
    }
  };

  // ---- stage 1 pipelined loop: 1 barrier/chunk, counted vmcnt ----
  issue(0, 0);
  // peel i=0: full drain (only batch-0 outstanding)
  __builtin_amdgcn_sched_barrier(0);
  asm volatile("s_waitcnt vmcnt(0)" ::: "memory");
  __builtin_amdgcn_sched_barrier(0);
  __builtin_amdgcn_s_barrier();
  __builtin_amdgcn_sched_barrier(0);
  issue(1, 1);
  __builtin_amdgcn_sched_barrier(0);
  consume(0, (const float*)smem);
  slice(0, (const float*)smem);

#pragma unroll 2
  for (int i = 1; i < 12; ++i) {
    // Wave's vm queue at this point (oldest first): DMA(i) 2-3 ops,
    // consume(i-1) wfr loads 32, slice(i-1) stores <=8. vmcnt(16) retires
    // everything older than the newest 16 -> DMA(i) certainly landed,
    // while newer loads/stores stay in flight (never vmcnt(0) here).
    __builtin_amdgcn_sched_barrier(0);
    asm volatile("s_waitcnt vmcnt(16)" ::: "memory");
    __builtin_amdgcn_sched_barrier(0);
    __builtin_amdgcn_s_barrier();
    __builtin_amdgcn_sched_barrier(0);
    if (i + 1 < 12) issue(i + 1, (i + 1) & 1);
    __builtin_amdgcn_sched_barrier(0);     // pin consume below issue
    const float* bF = (const float*)(smem + (i & 1) * BUFB);
    consume(i, bF);
    slice(i, bF);
  }

  __syncthreads();   // all chunk reads done before Yb overlays buffers

  // ---- epilogue 1: bias + tanh*sigmoid -> Yb (bf16, swizzled) ----
#pragma unroll
  for (int mi = 0; mi < 4; ++mi) {
    const int mbase = w * 64 + mi * 16 + kq * 4;   // multiple of 4
    const f32x4 b4 = *(const f32x4*)&bias1[mbase];
#pragma unroll
    for (int ni = 0; ni < 4; ++ni) {
      f32x4 v = acc[mi][ni];
      float f0 = v.x + b4.x, g0 = v.y + b4.y, f1 = v.z + b4.z, g1 = v.w + b4.w;
      float y0 = (2.f / (1.f + __expf(-2.f * f0)) - 1.f) * (1.f / (1.f + __expf(-g0)));
      float y1 = (2.f / (1.f + __expf(-2.f * f1)) - 1.f) * (1.f / (1.f + __expf(-g1)));
      int n = ni * 16 + ln;
      uint32_t pk = (uint32_t)f2bf(y0) | ((uint32_t)f2bf(y1) << 16);
      int boff = (n * 512 + mbase) ^ ((n & 7) << 4);   // ch pair at byte mbase
      *(uint32_t*)(Yb + boff) = pk;
    }
  }
  __syncthreads();

  // ---- stage 2: [res;skip] = W2 * Y ----
  f32x4 acc2[4][4];
#pragma unroll
  for (int i = 0; i < 4; ++i)
#pragma unroll
    for (int j = 0; j < 4; ++j) acc2[i][j] = (f32x4){0.f, 0.f, 0.f, 0.f};

#pragma unroll
  for (int kf = 0; kf < 8; ++kf) {
    bf16x8 zfr[4];
#pragma unroll
    for (int ni = 0; ni < 4; ++ni) {
      int n = ni * 16 + ln;
      int boff = (n * 512 + kf * 64 + kq * 16) ^ ((n & 7) << 4);
      zfr[ni] = *(const bf16x8*)(Yb + boff);
    }
    bf16x8 wfr[4];
#pragma unroll
    for (int mi = 0; mi < 4; ++mi)
      wfr[mi] = *(const bf16x8*)
          &w2p[(size_t)(kf * 32 + (w * 4 + mi)) * 512 + lane * 8];
#pragma unroll
    for (int mi = 0; mi < 4; ++mi)
#pragma unroll
      for (int ni = 0; ni < 4; ++ni)
        acc2[mi][ni] = __builtin_amdgcn_mfma_f32_16x16x32_bf16(
            wfr[mi], zfr[ni], acc2[mi][ni], 0, 0, 0);
  }

  // ---- epilogue 2: bias + residual adds, store res / skips_out ----
#pragma unroll
  for (int mi = 0; mi < 4; ++mi) {
    const int mbase = w * 64 + mi * 16 + kq * 4;
    const f32x4 b4 = *(const f32x4*)&bias2[mbase];
#pragma unroll
    for (int r = 0; r < 4; ++r) {
      const int m2 = mbase + r;
      const int isres = (m2 < 256);            // uniform per wave (w<4)
      const int crow = isres ? m2 : m2 - 256;
      const float* ap = (isres ? x : skips) + ((size_t)(bb * C_ + crow)) * T_ + t0 + 2;
      float* dp = (isres ? out0 : out3) + ((size_t)(bb * C_ + crow)) * TOUT + t0;
      const float bs = b4[r];
#pragma unroll
      for (int ni = 0; ni < 4; ++ni) {
        int n = ni * 16 + ln;
        if (n < valid) dp[n] = acc2[mi][ni][r] + bs + ap[n];
      }
    }
  }
}

extern "C" void kernel_launch(void* const* d_in, const int* in_sizes, int n_in,
                              void* d_out, int out_size, void* d_ws, size_t ws_size,
                              hipStream_t stream) {
  const float* xx    = (const float*)d_in[0];
  const float* cin   = (const float*)d_in[1];
  const float* gin   = (const float*)d_in[2];
  const float* skips = (const float*)d_in[3];
  const float* w_fx = (const float*)d_in[4],  *b_fx = (const float*)d_in[5];
  const float* w_fc = (const float*)d_in[6],  *b_fc = (const float*)d_in[7];
  const float* w_fg = (const float*)d_in[8],  *b_fg = (const float*)d_in[9];
  const float* w_gx = (const float*)d_in[10], *b_gx = (const float*)d_in[11];
  const float* w_gc = (const float*)d_in[12], *b_gc = (const float*)d_in[13];
  const float* w_gg = (const float*)d_in[14], *b_gg = (const float*)d_in[15];
  const float* w_res  = (const float*)d_in[16], *b_res  = (const float*)d_in[17];
  const float* w_skip = (const float*)d_in[18], *b_skip = (const float*)d_in[19];
  char* ws = (char*)d_ws;
  float* outp = (float*)d_out;

  prep_kernel<<<(N_W1 + N_W2 + 1024) / 256, 256, 0, stream>>>(
      w_fx, w_fc, w_fg, w_gx, w_gc, w_gg,
      b_fx, b_fc, b_fg, b_gx, b_gc, b_gg,
      w_res, b_res, w_skip, b_skip, ws);

  // 8 batches x 128 time-tiles of 64 (XCD-chunk-swizzled in-kernel)
  wavenet_kernel<<<1024, 512, 0, stream>>>(xx, cin, gin, skips, ws, outp);
}